// Round 6
// baseline (3442.986 us; speedup 1.0000x reference)
//
#include <hip/hip_runtime.h>
#include <stdint.h>

typedef unsigned short u16;
typedef unsigned int u32;
typedef unsigned long long u64;
typedef __attribute__((ext_vector_type(8))) short bf16x8;
typedef __attribute__((ext_vector_type(4))) float f32x4;
typedef __attribute__((ext_vector_type(4))) u16 u16x4;
typedef __attribute__((ext_vector_type(2))) u64 u64x2;

#define T_STEPS 256
#define BATCH 64
#define IDIM 1024
#define HDIM 1024
#define NBLK 256
#define NJ 4            // h-columns per block
#define KPAD 2056       // padded K stride (bf16 elems) for LDS W
#define THREADS 512
#define FLAG_LINE_U32 16                       // 64 B spacing
#define GO_U32 (NBLK * FLAG_LINE_U32)          // go lines (heavy barrier only)
#define X_OFF 262144                           // bytes into ws (same as r1/4/5)
#define H_OFF (X_OFF + T_STEPS * BATCH * IDIM * 2)  // bytes into ws
#define LDS_BYTES 83712  // 65792 (W) + 17408 (cand) + 512 (hstage)

static __device__ __forceinline__ u16 f2bf(float f) {
  u32 u = __builtin_bit_cast(u32, f);
  u += 0x7FFFu + ((u >> 16) & 1u);
  return (u16)(u >> 16);
}
static __device__ __forceinline__ float sigf(float x) {
  return __builtin_amdgcn_rcpf(1.f + __expf(-x));
}
static __device__ __forceinline__ float tanhf_(float x) {
  float ax = __builtin_fabsf(x);
  float e = __expf(-2.f * ax);
  float t = 1.f - 2.f * e * __builtin_amdgcn_rcpf(1.f + e);
  return __builtin_copysignf(t, x);
}

// Heavy full barrier: used ONCE (epoch 1) to make cached xbf/h0 writes
// visible (threadfence release/acquire). Same code that ran in rounds 4/5.
static __device__ __forceinline__ void gbar_heavy(u32* flags, u32* go, int bid,
                                                  int tid) {
  __syncthreads();
  if (tid == 0) {
    __threadfence();  // release: wbl2 so cached xbf writes visible
    __hip_atomic_store(&flags[bid * FLAG_LINE_U32], 1u, __ATOMIC_RELAXED,
                       __HIP_MEMORY_SCOPE_AGENT);
  }
  if (bid == 0) {
    if (tid < NBLK) {
      while (__hip_atomic_load(&flags[tid * FLAG_LINE_U32], __ATOMIC_RELAXED,
                               __HIP_MEMORY_SCOPE_AGENT) < 1u)
        __builtin_amdgcn_s_sleep(1);
    }
    __syncthreads();
    if (tid < 8)
      __hip_atomic_store(&go[tid * FLAG_LINE_U32], 1u, __ATOMIC_RELAXED,
                         __HIP_MEMORY_SCOPE_AGENT);
  } else {
    if (tid == 0) {
      while (__hip_atomic_load(&go[(bid & 7) * FLAG_LINE_U32], __ATOMIC_RELAXED,
                               __HIP_MEMORY_SCOPE_AGENT) < 1u)
        __builtin_amdgcn_s_sleep(2);
    }
  }
  if (tid == 0) __threadfence();  // acquire: invalidate L1/L2 before reads
  __syncthreads();
}

// ---- DATAFLOW LSTM: no grid barrier in the steady loop ----
// Rounds 0-5 falsified every component-level barrier theory (h-path, arrive
// RMW, out RFO); three barrier topologies all cost ~10-13us/step while work
// is ~1.5us. The barrier STRUCTURE (all-wait + central detect + release +
// L2-invalidate + max-skew over 256 blocks) is the floor. This version
// removes it: block p publishes h-cols [4p,4p+4) (sc1, wave-drained) then
// sets flags[p]=t+2. An h-wave's k-range depends on 128 known producers;
// it consumes in 4 groups of 32 producers (128 k-elems = 4 ks each):
// poll those 32 flags (lane-parallel, one group prefetched ahead so poll
// latency hides under MFMAs), then MFMA that group with agent-scope u64
// h-loads (round-0-proven coherent path; always fresh -> NO L2 invalidate,
// x/W stay L2-hot forever). x-waves never wait. Safety: 2-buffer hbuf is
// race-free by publication-gating (step-t+2 writes to buf[t&1] are gated on
// all flags>=t+3, i.e. every block's step-t+1 reads completed); monotonic
// epochs, no reset; deadlock-free by induction (flag t+2 depends only on
// flags t+1). Flag loads are ordered before dependent h-loads by the
// branch; h visibility is guaranteed by the producer's wave-local
// s_waitcnt vmcnt(0) between publish and flag store.
__global__ __launch_bounds__(THREADS, 2)
void lstm_persistent(const float* __restrict__ x, const float* __restrict__ h0,
                     const float* __restrict__ c0, const float* __restrict__ W,
                     const float* __restrict__ bias, const int* __restrict__ L,
                     float* __restrict__ out, u16* __restrict__ xbf,
                     u16* __restrict__ hbuf, u32* __restrict__ flags) {
  extern __shared__ char smem[];
  u16* Wlds = (u16*)smem;                 // [16 cols][KPAD] bf16 = 65792 B
  float* cand = (float*)(smem + 65792);   // [4 kq][64 b][17] f32 = 17408 B
  u16* hstage = (u16*)(smem + 83200);     // [256] bf16 staging = 512 B

  u32* go = flags + GO_U32;

  const int bid = blockIdx.x;
  const int tid = threadIdx.x;
  const int wave = tid >> 6;
  const int lane = tid & 63;
  const int q = lane >> 4;   // quad 0..3
  const int ln = lane & 15;
  const int mh = wave & 1;   // M half: rows [32*mh, 32*mh+32)
  const int kh = wave >> 1;  // K quarter: k in [kh*512, kh*512+512)

  // ---- phase 0a: x -> bf16 (grid-wide), h0 -> bf16 into hbuf[1] ----
  {
    const int gtid = bid * THREADS + tid;
    const f32x4* xv = (const f32x4*)x;
    u16x4* ov = (u16x4*)xbf;
#pragma unroll
    for (int it = 0; it < 32; ++it) {
      int i = gtid + it * (NBLK * THREADS);
      f32x4 v = xv[i];
      u16x4 o;
      o[0] = f2bf(v[0]); o[1] = f2bf(v[1]); o[2] = f2bf(v[2]); o[3] = f2bf(v[3]);
      ov[i] = o;
    }
    if (gtid < BATCH * HDIM) hbuf[BATCH * HDIM + gtid] = f2bf(h0[gtid]);
  }

  // ---- phase 0b: W slice -> LDS (bf16, column-major with K pad) ----
  {
    const int g = tid & 3;
    const int kq2 = tid >> 2;  // 0..127
    const f32x4* Wv = (const f32x4*)W;  // one W row = 1024 f32x4
#pragma unroll 4
    for (int i = 0; i < 16; ++i) {
      int k = kq2 + 128 * i;
      f32x4 w4 = Wv[(size_t)k * 1024 + g * 256 + bid];
#pragma unroll
      for (int jj = 0; jj < 4; ++jj)
        Wlds[(g * 4 + jj) * KPAD + k] = f2bf(w4[jj]);
    }
  }

  // ---- per-thread pointwise state (threads 0..255: (b, j) pairs) ----
  float c_reg = 0.f, h_reg = 0.f, b_i = 0.f, b_f = 0.f, b_o = 0.f, b_g = 0.f;
  int Lb = 0, pb = 0, pj = 0;
  if (tid < 256) {
    pb = tid >> 2;
    pj = tid & 3;
    int gj = bid * NJ + pj;
    Lb = L[pb];
    c_reg = c0[pb * HDIM + gj];
    h_reg = h0[pb * HDIM + gj];
    b_i = bias[0 * HDIM + gj];
    b_f = bias[1 * HDIM + gj];
    b_o = bias[2 * HDIM + gj];
    b_g = bias[3 * HDIM + gj];
  }

  gbar_heavy(flags, go, bid, tid);  // epoch 1: x/h0 visible; flags[*]=1

  const int arow = 32 * mh + ln;        // batch row of this wave's tile0
  const bool fromx = (kh < 2);
  const int kbase = (kh & 1) * 512;     // k offset within source (x or h)
  const int pbase = kbase >> 2;         // first producer block of my k-range
  const u16* wp = &Wlds[ln * KPAD + kh * 512 + q * 8];

  for (int t = 0; t < T_STEPS; ++t) {
    f32x4 acc0 = {0.f, 0.f, 0.f, 0.f};
    f32x4 acc1 = {0.f, 0.f, 0.f, 0.f};
    if (fromx) {
      // x-waves: never wait. Plain cached loads; x/W stay L2-hot (no inv).
      const u16* pa0 =
          xbf + (size_t)t * (BATCH * IDIM) + arow * 1024 + kbase + q * 8;
      const u16* pa1 = pa0 + 16 * 1024;
#pragma unroll
      for (int ks = 0; ks < 16; ++ks) {
        bf16x8 a0 = *(const bf16x8*)(pa0 + ks * 32);
        bf16x8 a1 = *(const bf16x8*)(pa1 + ks * 32);
        bf16x8 bw = *(const bf16x8*)(wp + ks * 32);
        acc0 = __builtin_amdgcn_mfma_f32_16x16x32_bf16(a0, bw, acc0, 0, 0, 0);
        acc1 = __builtin_amdgcn_mfma_f32_16x16x32_bf16(a1, bw, acc1, 0, 0, 0);
      }
    } else {
      // h-waves: grouped dataflow consume. Group g = 32 producers = 4 ks.
      const u32 e = (u32)(t + 1);  // producers of h(t-1) set flag = t+1
      const u16* pa0 = hbuf + ((t + 1) & 1) * (BATCH * HDIM) + arow * 1024 +
                       kbase + q * 8;
      const u16* pa1 = pa0 + 16 * 1024;
      u32 fv = __hip_atomic_load(
          &flags[(pbase + (lane & 31)) * FLAG_LINE_U32], __ATOMIC_RELAXED,
          __HIP_MEMORY_SCOPE_AGENT);
#pragma unroll
      for (int g = 0; g < 4; ++g) {
        while (!__all(fv >= e)) {
          __builtin_amdgcn_s_sleep(1);
          fv = __hip_atomic_load(
              &flags[(pbase + g * 32 + (lane & 31)) * FLAG_LINE_U32],
              __ATOMIC_RELAXED, __HIP_MEMORY_SCOPE_AGENT);
        }
        // Prefetch next group's flags; the compare happens after this
        // group's MFMAs, so the load latency hides under compute.
        u32 fnext = e;
        if (g < 3)
          fnext = __hip_atomic_load(
              &flags[(pbase + (g + 1) * 32 + (lane & 31)) * FLAG_LINE_U32],
              __ATOMIC_RELAXED, __HIP_MEMORY_SCOPE_AGENT);
#pragma unroll
        for (int ks = g * 4; ks < g * 4 + 4; ++ks) {
          u64x2 r0, r1;
          r0[0] = __hip_atomic_load((const u64*)(pa0 + ks * 32),
                                    __ATOMIC_RELAXED, __HIP_MEMORY_SCOPE_AGENT);
          r0[1] = __hip_atomic_load((const u64*)(pa0 + ks * 32 + 4),
                                    __ATOMIC_RELAXED, __HIP_MEMORY_SCOPE_AGENT);
          r1[0] = __hip_atomic_load((const u64*)(pa1 + ks * 32),
                                    __ATOMIC_RELAXED, __HIP_MEMORY_SCOPE_AGENT);
          r1[1] = __hip_atomic_load((const u64*)(pa1 + ks * 32 + 4),
                                    __ATOMIC_RELAXED, __HIP_MEMORY_SCOPE_AGENT);
          bf16x8 a0 = __builtin_bit_cast(bf16x8, r0);
          bf16x8 a1 = __builtin_bit_cast(bf16x8, r1);
          bf16x8 bw = *(const bf16x8*)(wp + ks * 32);
          acc0 = __builtin_amdgcn_mfma_f32_16x16x32_bf16(a0, bw, acc0, 0, 0, 0);
          acc1 = __builtin_amdgcn_mfma_f32_16x16x32_bf16(a1, bw, acc1, 0, 0, 0);
        }
        fv = fnext;
      }
    }
    // C/D layout: col = lane&15, row-in-tile = quad*4 + reg  (m89-verified)
    {
      float* c0p = &cand[(kh * 64 + 32 * mh + q * 4) * 17 + ln];
      float* c1p = c0p + 16 * 17;
#pragma unroll
      for (int r = 0; r < 4; ++r) {
        c0p[r * 17] = acc0[r];
        c1p[r * 17] = acc1[r];
      }
    }
    __syncthreads();
    if (tid < 256) {
      float vi = b_i, vf = b_f, vo = b_o, vg = b_g;
#pragma unroll
      for (int p = 0; p < 4; ++p) {
        const float* cp = &cand[(p * 64 + pb) * 17];
        vi += cp[pj];
        vf += cp[4 + pj];
        vo += cp[8 + pj];
        vg += cp[12 + pj];
      }
      float ig = sigf(vi), fg = sigf(vf), og = sigf(vo), gg = tanhf_(vg);
      float cn = ig * gg + fg * c_reg;
      float hn = og * tanhf_(cn);
      if (t < Lb) { c_reg = cn; h_reg = hn; }  // freeze past sequence end
      // out early: its sc1 store drains together with the publish drain
      // (round-5 post-mortem: trailing stores sneak back into the next
      // step's vmcnt waits, so retire them with the publish).
      __hip_atomic_store(&out[((size_t)t * BATCH + pb) * HDIM + bid * NJ + pj],
                         h_reg, __ATOMIC_RELAXED, __HIP_MEMORY_SCOPE_AGENT);
      hstage[tid] = f2bf(h_reg);
    }
    __syncthreads();
    if (t < T_STEPS - 1) {
      if (tid < 64) {
        // publish h: device-scope u64 stores (4 bf16), write-through to IF$
        u64 v = ((const u64*)hstage)[tid];
        u64* dst =
            (u64*)(hbuf + (t & 1) * (BATCH * HDIM) + tid * HDIM + bid * NJ);
        __hip_atomic_store(dst, v, __ATOMIC_RELAXED, __HIP_MEMORY_SCOPE_AGENT);
        // wave-local drain: publish at IF$ before the flag store; other
        // waves are NOT blocked (no block-wide barrier here).
        asm volatile("s_waitcnt vmcnt(0)" ::: "memory");
      }
      if (tid == 0)
        __hip_atomic_store(&flags[bid * FLAG_LINE_U32], (u32)(t + 2),
                           __ATOMIC_RELAXED, __HIP_MEMORY_SCOPE_AGENT);
    }
  }
}

extern "C" void kernel_launch(void* const* d_in, const int* in_sizes, int n_in,
                              void* d_out, int out_size, void* d_ws, size_t ws_size,
                              hipStream_t stream) {
  (void)in_sizes; (void)n_in; (void)out_size; (void)ws_size;
  const float* x = (const float*)d_in[0];
  const float* h0 = (const float*)d_in[1];
  const float* c0 = (const float*)d_in[2];
  const float* W = (const float*)d_in[3];
  const float* bias = (const float*)d_in[4];
  const int* L = (const int*)d_in[5];
  float* out = (float*)d_out;

  char* ws = (char*)d_ws;
  u32* flags = (u32*)ws;
  u16* xbf = (u16*)(ws + X_OFF);
  u16* hbuf = (u16*)(ws + H_OFF);

  hipFuncSetAttribute(reinterpret_cast<const void*>(lstm_persistent),
                      hipFuncAttributeMaxDynamicSharedMemorySize, 160 * 1024);
  hipMemsetAsync(ws, 0, 32768, stream);  // zero flags + go lines
  hipLaunchKernelGGL(lstm_persistent, dim3(NBLK), dim3(THREADS), LDS_BYTES,
                     stream, x, h0, c0, W, bias, L, out, xbf, hbuf, flags);
}

// Round 7
// 2902.509 us; speedup vs baseline: 1.1862x; 1.1862x over previous
//
#include <hip/hip_runtime.h>
#include <stdint.h>

typedef unsigned short u16;
typedef unsigned int u32;
typedef unsigned long long u64;
typedef __attribute__((ext_vector_type(8))) short bf16x8;
typedef __attribute__((ext_vector_type(4))) float f32x4;
typedef __attribute__((ext_vector_type(4))) u16 u16x4;

#define T_STEPS 256
#define BATCH 64
#define IDIM 1024
#define HDIM 1024
#define NBLK 256
#define NJ 4            // h-columns per block
#define KPAD 2056       // padded K stride (bf16 elems) for LDS W
#define THREADS 256     // 4 waves; each owns one 16-batch M-tile, full K
#define FLAG_LINE_U32 16                       // 64 B spacing
#define GO_U32 (NBLK * FLAG_LINE_U32)          // go lines after arrive flags
#define X_OFF 262144                           // bytes into ws (same as r1/4/5)
#define H_OFF (X_OFF + T_STEPS * BATCH * IDIM * 2)  // bytes into ws
#define LDS_BYTES 65792  // W only — cand/hstage eliminated (wave-local pointwise)

static __device__ __forceinline__ u16 f2bf(float f) {
  u32 u = __builtin_bit_cast(u32, f);
  u += 0x7FFFu + ((u >> 16) & 1u);
  return (u16)(u >> 16);
}
static __device__ __forceinline__ float sigf(float x) {
  return __builtin_amdgcn_rcpf(1.f + __expf(-x));
}
static __device__ __forceinline__ float tanhf_(float x) {
  float ax = __builtin_fabsf(x);
  float e = __expf(-2.f * ax);
  float t = 1.f - 2.f * e * __builtin_amdgcn_rcpf(1.f + e);
  return __builtin_copysignf(t, x);
}

// ---- round-5 split-phase barrier (proven, unchanged mechanism) ----
// R6 post-mortem: dataflow+sc1-loads regressed to R0 levels (sc1 tax +
// lost overlaps, detect==release latency). Frame stays R5: store-arrive,
// block-0 wave-parallel watcher, 8 go lines, cached h + one acquire-inv
// per step. This round instead removes the INTRA-block superstructure
// (see kernel comment). Watcher wave here is wave 3 (of 4).
static __device__ __forceinline__ void gwait(u32* flags, u32* go, u32 e,
                                             int bid, int tid, int lane) {
  if (bid == 0) {
    if ((tid >> 6) == 3) {  // wave 3: wave-parallel watcher
      const u32* p0 = &flags[lane * FLAG_LINE_U32];
      const u32* p1 = &flags[(lane + 64) * FLAG_LINE_U32];
      const u32* p2 = &flags[(lane + 128) * FLAG_LINE_U32];
      const u32* p3 = &flags[(lane + 192) * FLAG_LINE_U32];
      while (true) {
        u32 a = __hip_atomic_load(p0, __ATOMIC_RELAXED, __HIP_MEMORY_SCOPE_AGENT);
        u32 b = __hip_atomic_load(p1, __ATOMIC_RELAXED, __HIP_MEMORY_SCOPE_AGENT);
        u32 c = __hip_atomic_load(p2, __ATOMIC_RELAXED, __HIP_MEMORY_SCOPE_AGENT);
        u32 d = __hip_atomic_load(p3, __ATOMIC_RELAXED, __HIP_MEMORY_SCOPE_AGENT);
        int mine = (a >= e) && (b >= e) && (c >= e) && (d >= e);
        if (__all(mine)) break;
        __builtin_amdgcn_s_sleep(1);
      }
      if (lane < 8)
        __hip_atomic_store(&go[lane * FLAG_LINE_U32], e, __ATOMIC_RELAXED,
                           __HIP_MEMORY_SCOPE_AGENT);
    }
  } else {
    if (tid == 192) {  // lane 0 of wave 3
      while (__hip_atomic_load(&go[(bid & 7) * FLAG_LINE_U32], __ATOMIC_RELAXED,
                               __HIP_MEMORY_SCOPE_AGENT) < e)
        __builtin_amdgcn_s_sleep(2);
    }
  }
  if (tid == 192)
    __builtin_amdgcn_fence(__ATOMIC_ACQUIRE, "agent");  // buffer_inv sc1
  __syncthreads();
}

// Heavy full barrier for epoch 1 only (xbf/h0 written with cached stores).
static __device__ __forceinline__ void gbar_heavy(u32* flags, u32* go, int bid,
                                                  int tid) {
  __syncthreads();
  if (tid == 0) {
    __threadfence();  // release: wbl2 so cached xbf writes visible
    __hip_atomic_store(&flags[bid * FLAG_LINE_U32], 1u, __ATOMIC_RELAXED,
                       __HIP_MEMORY_SCOPE_AGENT);
  }
  if (bid == 0) {
    if (tid < NBLK) {
      while (__hip_atomic_load(&flags[tid * FLAG_LINE_U32], __ATOMIC_RELAXED,
                               __HIP_MEMORY_SCOPE_AGENT) < 1u)
        __builtin_amdgcn_s_sleep(1);
    }
    __syncthreads();
    if (tid < 8)
      __hip_atomic_store(&go[tid * FLAG_LINE_U32], 1u, __ATOMIC_RELAXED,
                         __HIP_MEMORY_SCOPE_AGENT);
  } else {
    if (tid == 0) {
      while (__hip_atomic_load(&go[(bid & 7) * FLAG_LINE_U32], __ATOMIC_RELAXED,
                               __HIP_MEMORY_SCOPE_AGENT) < 1u)
        __builtin_amdgcn_s_sleep(2);
    }
  }
  if (tid == 0) __threadfence();  // acquire: invalidate L1/L2 before reads
  __syncthreads();
}

// ---- WAVE-LOCAL-POINTWISE LSTM ----
// R5's 10.2us/step = 0.45us MFMA + post-release tail + intra-block
// superstructure: 3 __syncthreads + cand-LDS + 256-thread pointwise +
// hstage-LDS existed only because K was split across waves (gate partials
// needed LDS reduction). New: 4 waves, each owns one 16-batch M-tile with
// FULL K=2048 (64 MFMAs, 2 interleaved accs to break the dependent chain).
// Each wave then holds COMPLETE gate sums: for output (b, j=ln<4), gates
// i/f/o/g sit in lanes ln, ln^4, ln^8, ln^12 of the SAME wave (C-layout:
// col=lane&15=gate-col, row=quad*4+r=batch; cols 0-3=i,4-7=f,8-11=o,
// 12-15=g). 3 shfl_xor replace the whole LDS reduction; ONE __syncthreads
// per step (publish drain) instead of three. x-half (ks 0-31) pre-wait
// (R5 win kept); h-half (ks 32-63) post-release with cached loads after
// the acquire-inv. Publish: lanes pack 4 cols into u64 via 2 shfl_xor,
// lane ln==0 stores 4 u64 (sc1); sync; tid0 flag; out stores off-chain.
__global__ __launch_bounds__(THREADS, 1)
void lstm_persistent(const float* __restrict__ x, const float* __restrict__ h0,
                     const float* __restrict__ c0, const float* __restrict__ W,
                     const float* __restrict__ bias, const int* __restrict__ L,
                     float* __restrict__ out, u16* __restrict__ xbf,
                     u16* __restrict__ hbuf, u32* __restrict__ flags) {
  extern __shared__ char smem[];
  u16* Wlds = (u16*)smem;  // [16 cols][KPAD] bf16 = 65792 B

  u32* go = flags + GO_U32;

  const int bid = blockIdx.x;
  const int tid = threadIdx.x;
  const int m = tid >> 6;    // wave 0..3: M-tile rows [16m, 16m+16)
  const int lane = tid & 63;
  const int q = lane >> 4;   // quad 0..3: k-offset q*8, batch sub-row q*4+r
  const int ln = lane & 15;  // gate-col 0..15; A-row = 16m+ln

  // ---- phase 0a: x -> bf16 (grid-wide), h0 -> bf16 into hbuf[1] ----
  {
    const int gtid = bid * THREADS + tid;
    const f32x4* xv = (const f32x4*)x;
    u16x4* ov = (u16x4*)xbf;
#pragma unroll
    for (int it = 0; it < 64; ++it) {
      int i = gtid + it * (NBLK * THREADS);
      f32x4 v = xv[i];
      u16x4 o;
      o[0] = f2bf(v[0]); o[1] = f2bf(v[1]); o[2] = f2bf(v[2]); o[3] = f2bf(v[3]);
      ov[i] = o;
    }
    if (gtid < BATCH * HDIM) hbuf[BATCH * HDIM + gtid] = f2bf(h0[gtid]);
  }

  // ---- phase 0b: W slice -> LDS (bf16, column-major with K pad) ----
  {
    const int g = tid & 3;
    const int kq2 = tid >> 2;  // 0..63
    const f32x4* Wv = (const f32x4*)W;  // one W row = 1024 f32x4
#pragma unroll 4
    for (int i = 0; i < 32; ++i) {
      int k = kq2 + 64 * i;
      f32x4 w4 = Wv[(size_t)k * 1024 + g * 256 + bid];
#pragma unroll
      for (int jj = 0; jj < 4; ++jj)
        Wlds[(g * 4 + jj) * KPAD + k] = f2bf(w4[jj]);
    }
  }

  // ---- per-lane pointwise state: lanes ln<4 own (batch=16m+4q+r, j=ln) ----
  const bool act = (ln < 4);
  float c_reg[4], h_reg[4];
  int Lb[4];
  float b_i = 0.f, b_f = 0.f, b_o = 0.f, b_g = 0.f;
#pragma unroll
  for (int r = 0; r < 4; ++r) { c_reg[r] = 0.f; h_reg[r] = 0.f; Lb[r] = 0; }
  if (act) {
    const int gj = bid * NJ + ln;
    b_i = bias[0 * HDIM + gj];
    b_f = bias[1 * HDIM + gj];
    b_o = bias[2 * HDIM + gj];
    b_g = bias[3 * HDIM + gj];
#pragma unroll
    for (int r = 0; r < 4; ++r) {
      const int b = 16 * m + 4 * q + r;
      Lb[r] = L[b];
      c_reg[r] = c0[b * HDIM + gj];
      h_reg[r] = h0[b * HDIM + gj];
    }
  }

  gbar_heavy(flags, go, bid, tid);  // epoch 1: x/h0 visible; flags[*]=1

  const u16* wp = &Wlds[ln * KPAD + q * 8];  // W col ln, k base q*8

  for (int t = 0; t < T_STEPS; ++t) {
    f32x4 acc0 = {0.f, 0.f, 0.f, 0.f};
    f32x4 acc1 = {0.f, 0.f, 0.f, 0.f};
    // ---- x-half (k 0..1023, h-independent): BEFORE the wait ----
    {
      const u16* pax =
          xbf + (size_t)t * (BATCH * IDIM) + (16 * m + ln) * 1024 + q * 8;
#pragma unroll
      for (int ks = 0; ks < 32; ++ks) {
        bf16x8 a = *(const bf16x8*)(pax + ks * 32);
        bf16x8 bw = *(const bf16x8*)(wp + ks * 32);
        if (ks & 1)
          acc1 = __builtin_amdgcn_mfma_f32_16x16x32_bf16(a, bw, acc1, 0, 0, 0);
        else
          acc0 = __builtin_amdgcn_mfma_f32_16x16x32_bf16(a, bw, acc0, 0, 0, 0);
      }
    }
    asm volatile("" ::"v"(acc0), "v"(acc1));  // pin: don't sink past wait
    __builtin_amdgcn_sched_barrier(0);

    // ---- wait for h(t-1) published (epoch t+1); t=0 covered by heavy ----
    if (t > 0) gwait(flags, go, (u32)(t + 1), bid, tid, lane);

    // ---- h-half (k 1024..2047): cached loads, fresh after acquire-inv ----
    {
      const u16* pah = hbuf + ((t + 1) & 1) * (BATCH * HDIM) +
                       (16 * m + ln) * 1024 + q * 8;
      const u16* wph = wp + 1024;
#pragma unroll
      for (int ks = 0; ks < 32; ++ks) {
        bf16x8 a = *(const bf16x8*)(pah + ks * 32);
        bf16x8 bw = *(const bf16x8*)(wph + ks * 32);
        if (ks & 1)
          acc1 = __builtin_amdgcn_mfma_f32_16x16x32_bf16(a, bw, acc1, 0, 0, 0);
        else
          acc0 = __builtin_amdgcn_mfma_f32_16x16x32_bf16(a, bw, acc0, 0, 0, 0);
      }
    }
    // ---- wave-local pointwise: gates i/f/o/g at lanes ln,ln^4,ln^8,ln^12 ----
    f32x4 s = acc0 + acc1;
    float sf[4], so[4], sg[4];
#pragma unroll
    for (int r = 0; r < 4; ++r) {
      sf[r] = __shfl_xor(s[r], 4);
      so[r] = __shfl_xor(s[r], 8);
      sg[r] = __shfl_xor(s[r], 12);
    }
    if (act) {
#pragma unroll
      for (int r = 0; r < 4; ++r) {
        float vi = s[r] + b_i, vf = sf[r] + b_f, vo = so[r] + b_o,
              vg = sg[r] + b_g;
        float ig = sigf(vi), fg = sigf(vf), og = sigf(vo), gg = tanhf_(vg);
        float cn = ig * gg + fg * c_reg[r];
        float hn = og * tanhf_(cn);
        if (t < Lb[r]) { c_reg[r] = cn; h_reg[r] = hn; }  // freeze past end
      }
    }
    // ---- pack 4 cols -> u64 per batch (2 shfl_xor), publish + flag ----
    if (t < T_STEPS - 1) {
      u32 v[4];
#pragma unroll
      for (int r = 0; r < 4; ++r) v[r] = (u32)f2bf(h_reg[r]);
#pragma unroll
      for (int r = 0; r < 4; ++r) {
        u32 a32 = v[r] | (((u32)__shfl_xor((int)v[r], 1)) << 16);
        u32 b32 = (u32)__shfl_xor((int)a32, 2);
        if (ln == 0) {
          u64 w = (u64)a32 | ((u64)b32 << 32);
          u64* dst = (u64*)(hbuf + (t & 1) * (BATCH * HDIM) +
                            (16 * m + 4 * q + r) * HDIM + bid * NJ);
          __hip_atomic_store(dst, w, __ATOMIC_RELAXED,
                             __HIP_MEMORY_SCOPE_AGENT);
        }
      }
      __syncthreads();  // vmcnt(0) drain: publish at IF$ before arrive
      if (tid == 0)
        __hip_atomic_store(&flags[bid * FLAG_LINE_U32], (u32)(t + 2),
                           __ATOMIC_RELAXED, __HIP_MEMORY_SCOPE_AGENT);
    }
    // ---- out stores LAST (sc1, off the critical chain) ----
    if (act) {
#pragma unroll
      for (int r = 0; r < 4; ++r)
        __hip_atomic_store(
            &out[((size_t)t * BATCH + 16 * m + 4 * q + r) * HDIM + bid * NJ + ln],
            h_reg[r], __ATOMIC_RELAXED, __HIP_MEMORY_SCOPE_AGENT);
    }
  }
}

extern "C" void kernel_launch(void* const* d_in, const int* in_sizes, int n_in,
                              void* d_out, int out_size, void* d_ws, size_t ws_size,
                              hipStream_t stream) {
  (void)in_sizes; (void)n_in; (void)out_size; (void)ws_size;
  const float* x = (const float*)d_in[0];
  const float* h0 = (const float*)d_in[1];
  const float* c0 = (const float*)d_in[2];
  const float* W = (const float*)d_in[3];
  const float* bias = (const float*)d_in[4];
  const int* L = (const int*)d_in[5];
  float* out = (float*)d_out;

  char* ws = (char*)d_ws;
  u32* flags = (u32*)ws;
  u16* xbf = (u16*)(ws + X_OFF);
  u16* hbuf = (u16*)(ws + H_OFF);

  hipFuncSetAttribute(reinterpret_cast<const void*>(lstm_persistent),
                      hipFuncAttributeMaxDynamicSharedMemorySize, 160 * 1024);
  hipMemsetAsync(ws, 0, 32768, stream);  // zero arrive flags + go lines
  hipLaunchKernelGGL(lstm_persistent, dim3(NBLK), dim3(THREADS), LDS_BYTES,
                     stream, x, h0, c0, W, bias, L, out, xbf, hbuf, flags);
}

// Round 8
// 2477.975 us; speedup vs baseline: 1.3894x; 1.1713x over previous
//
#include <hip/hip_runtime.h>
#include <stdint.h>

typedef unsigned short u16;
typedef unsigned int u32;
typedef unsigned long long u64;
typedef __attribute__((ext_vector_type(8))) short bf16x8;
typedef __attribute__((ext_vector_type(4))) float f32x4;
typedef __attribute__((ext_vector_type(4))) u16 u16x4;
typedef __attribute__((ext_vector_type(2))) u64 u64x2;

#define T_STEPS 256
#define BATCH 64
#define IDIM 1024
#define HDIM 1024
#define NBLK 256
#define NJ 4            // h-columns per block
#define KPAD 2056       // padded K stride (bf16 elems) for LDS W
#define THREADS 512
#define FLAG_LINE_U32 16                       // 64 B spacing
#define GO_U32 (NBLK * FLAG_LINE_U32)          // go lines after arrive flags
#define X_OFF 262144                           // bytes into ws (same as r1/4/5)
#define H_OFF (X_OFF + T_STEPS * BATCH * IDIM * 2)  // bytes into ws
#define LDS_BYTES 83712  // 65792 (W) + 17408 (cand) + 512 (hstage)

static __device__ __forceinline__ u16 f2bf(float f) {
  u32 u = __builtin_bit_cast(u32, f);
  u += 0x7FFFu + ((u >> 16) & 1u);
  return (u16)(u >> 16);
}
static __device__ __forceinline__ float sigf(float x) {
  return __builtin_amdgcn_rcpf(1.f + __expf(-x));
}
static __device__ __forceinline__ float tanhf_(float x) {
  float ax = __builtin_fabsf(x);
  float e = __expf(-2.f * ax);
  float t = 1.f - 2.f * e * __builtin_amdgcn_rcpf(1.f + e);
  return __builtin_copysignf(t, x);
}

// ---- round-5 split-phase barrier (proven, byte-identical mechanism) ----
// R7 post-mortem: wave-local pointwise regressed (occupancy halved, serial
// chain doubled). Frame returns to R5 (512 thr, 8 waves, cand-LDS). This
// round attacks the two untouched tail components instead:
//  (1) idle-half scheduling: ALL 8 waves now do 8 x-ks BEFORE the wait and
//      8 h-ks after it (R5: 4 waves idled pre-wait, 4 idled post-release).
//      Post-release serial tail (h loads+MFMAs) halves.
//  (2) publish line-sharing: hbuf becomes BLOCK-MAJOR [p][row][4cols] so
//      each block publishes ONE coalesced 512B wave-store to 8 EXCLUSIVE
//      64B lines (was: 8B sectors into lines shared by 8 blocks -> 16K
//      serialized partial-line write-throughs/step at the IF$).
static __device__ __forceinline__ void gwait(u32* flags, u32* go, u32 e,
                                             int bid, int tid, int lane) {
  if (bid == 0) {
    if ((tid >> 6) == 7) {  // wave 7: wave-parallel watcher
      const u32* p0 = &flags[lane * FLAG_LINE_U32];
      const u32* p1 = &flags[(lane + 64) * FLAG_LINE_U32];
      const u32* p2 = &flags[(lane + 128) * FLAG_LINE_U32];
      const u32* p3 = &flags[(lane + 192) * FLAG_LINE_U32];
      while (true) {
        u32 a = __hip_atomic_load(p0, __ATOMIC_RELAXED, __HIP_MEMORY_SCOPE_AGENT);
        u32 b = __hip_atomic_load(p1, __ATOMIC_RELAXED, __HIP_MEMORY_SCOPE_AGENT);
        u32 c = __hip_atomic_load(p2, __ATOMIC_RELAXED, __HIP_MEMORY_SCOPE_AGENT);
        u32 d = __hip_atomic_load(p3, __ATOMIC_RELAXED, __HIP_MEMORY_SCOPE_AGENT);
        int mine = (a >= e) && (b >= e) && (c >= e) && (d >= e);
        if (__all(mine)) break;
        __builtin_amdgcn_s_sleep(1);
      }
      if (lane < 8)
        __hip_atomic_store(&go[lane * FLAG_LINE_U32], e, __ATOMIC_RELAXED,
                           __HIP_MEMORY_SCOPE_AGENT);
    }
  } else {
    if (tid == 448) {  // lane 0 of wave 7: polls AFTER its x-phase (overlap)
      while (__hip_atomic_load(&go[(bid & 7) * FLAG_LINE_U32], __ATOMIC_RELAXED,
                               __HIP_MEMORY_SCOPE_AGENT) < e)
        __builtin_amdgcn_s_sleep(2);
    }
  }
  if (tid == 448)
    __builtin_amdgcn_fence(__ATOMIC_ACQUIRE, "agent");  // buffer_inv sc1
  __syncthreads();
}

// Heavy full barrier for epoch 1 only (xbf/h0 written with cached stores).
static __device__ __forceinline__ void gbar_heavy(u32* flags, u32* go, int bid,
                                                  int tid) {
  __syncthreads();
  if (tid == 0) {
    __threadfence();  // release: wbl2 so cached xbf writes visible
    __hip_atomic_store(&flags[bid * FLAG_LINE_U32], 1u, __ATOMIC_RELAXED,
                       __HIP_MEMORY_SCOPE_AGENT);
  }
  if (bid == 0) {
    if (tid < NBLK) {
      while (__hip_atomic_load(&flags[tid * FLAG_LINE_U32], __ATOMIC_RELAXED,
                               __HIP_MEMORY_SCOPE_AGENT) < 1u)
        __builtin_amdgcn_s_sleep(1);
    }
    __syncthreads();
    if (tid < 8)
      __hip_atomic_store(&go[tid * FLAG_LINE_U32], 1u, __ATOMIC_RELAXED,
                         __HIP_MEMORY_SCOPE_AGENT);
  } else {
    if (tid == 0) {
      while (__hip_atomic_load(&go[(bid & 7) * FLAG_LINE_U32], __ATOMIC_RELAXED,
                               __HIP_MEMORY_SCOPE_AGENT) < 1u)
        __builtin_amdgcn_s_sleep(2);
    }
  }
  if (tid == 0) __threadfence();  // acquire: invalidate L1/L2 before reads
  __syncthreads();
}

__global__ __launch_bounds__(THREADS, 2)
void lstm_persistent(const float* __restrict__ x, const float* __restrict__ h0,
                     const float* __restrict__ c0, const float* __restrict__ W,
                     const float* __restrict__ bias, const int* __restrict__ L,
                     float* __restrict__ out, u16* __restrict__ xbf,
                     u16* __restrict__ hbuf, u32* __restrict__ flags) {
  extern __shared__ char smem[];
  u16* Wlds = (u16*)smem;                 // [16 cols][KPAD] bf16 = 65792 B
  float* cand = (float*)(smem + 65792);   // [8 slot][32 row][17] f32 = 17408 B
  u16* hstage = (u16*)(smem + 83200);     // [256] bf16 staging = 512 B

  u32* go = flags + GO_U32;

  const int bid = blockIdx.x;
  const int tid = threadIdx.x;
  const int wave = tid >> 6;
  const int lane = tid & 63;
  const int q = lane >> 4;   // quad 0..3
  const int ln = lane & 15;
  const int mh = wave & 1;   // M half: rows [32*mh, 32*mh+32)
  const int kq = wave >> 1;  // K quarter: x-k in [kq*256,+256), h-k same +1024
  const int arow = 32 * mh + ln;

  // ---- phase 0a: x -> bf16 (grid-wide), h0 -> bf16 BLOCK-MAJOR hbuf[1] ----
  {
    const int gtid = bid * THREADS + tid;
    const f32x4* xv = (const f32x4*)x;
    u16x4* ov = (u16x4*)xbf;
#pragma unroll
    for (int it = 0; it < 32; ++it) {
      int i = gtid + it * (NBLK * THREADS);
      f32x4 v = xv[i];
      u16x4 o;
      o[0] = f2bf(v[0]); o[1] = f2bf(v[1]); o[2] = f2bf(v[2]); o[3] = f2bf(v[3]);
      ov[i] = o;
    }
    if (gtid < BATCH * HDIM) {
      // block-major: h[b][j] -> hbuf[buf1][(j>>2)*256 + b*4 + (j&3)]
      int b = gtid >> 10, j = gtid & 1023;
      hbuf[BATCH * HDIM + (j >> 2) * 256 + b * 4 + (j & 3)] = f2bf(h0[gtid]);
    }
  }

  // ---- phase 0b: W slice -> LDS (bf16, column-major with K pad) ----
  {
    const int g = tid & 3;
    const int kq2 = tid >> 2;  // 0..127
    const f32x4* Wv = (const f32x4*)W;  // one W row = 1024 f32x4
#pragma unroll 4
    for (int i = 0; i < 16; ++i) {
      int k = kq2 + 128 * i;
      f32x4 w4 = Wv[(size_t)k * 1024 + g * 256 + bid];
#pragma unroll
      for (int jj = 0; jj < 4; ++jj)
        Wlds[(g * 4 + jj) * KPAD + k] = f2bf(w4[jj]);
    }
  }

  // ---- per-thread pointwise state (threads 0..255: (b, j) pairs) ----
  float c_reg = 0.f, h_reg = 0.f, b_i = 0.f, b_f = 0.f, b_o = 0.f, b_g = 0.f;
  int Lb = 0, pb = 0, pj = 0;
  if (tid < 256) {
    pb = tid >> 2;
    pj = tid & 3;
    int gj = bid * NJ + pj;
    Lb = L[pb];
    c_reg = c0[pb * HDIM + gj];
    h_reg = h0[pb * HDIM + gj];
    b_i = bias[0 * HDIM + gj];
    b_f = bias[1 * HDIM + gj];
    b_o = bias[2 * HDIM + gj];
    b_g = bias[3 * HDIM + gj];
  }

  gbar_heavy(flags, go, bid, tid);  // epoch 1: x/h0 visible; flags[*]=1

  const u16* wpx = &Wlds[ln * KPAD + kq * 256 + q * 8];         // x K-quarter
  const u16* wph = &Wlds[ln * KPAD + 1024 + kq * 256 + q * 8];  // h K-quarter

  for (int t = 0; t < T_STEPS; ++t) {
    f32x4 acc0 = {0.f, 0.f, 0.f, 0.f};
    f32x4 acc1 = {0.f, 0.f, 0.f, 0.f};
    // ---- x-quarter (ALL waves, h-independent): BEFORE the wait ----
    {
      const u16* pa0 =
          xbf + (size_t)t * (BATCH * IDIM) + arow * 1024 + kq * 256 + q * 8;
      const u16* pa1 = pa0 + 16 * 1024;
#pragma unroll
      for (int ks = 0; ks < 8; ++ks) {
        bf16x8 a0 = *(const bf16x8*)(pa0 + ks * 32);
        bf16x8 a1 = *(const bf16x8*)(pa1 + ks * 32);
        bf16x8 bw = *(const bf16x8*)(wpx + ks * 32);
        acc0 = __builtin_amdgcn_mfma_f32_16x16x32_bf16(a0, bw, acc0, 0, 0, 0);
        acc1 = __builtin_amdgcn_mfma_f32_16x16x32_bf16(a1, bw, acc1, 0, 0, 0);
      }
    }
    asm volatile("" ::"v"(acc0), "v"(acc1));  // pin: don't sink past wait
    __builtin_amdgcn_sched_barrier(0);

    // ---- wait for h(t-1) published (epoch t+1); t=0 covered by heavy ----
    if (t > 0) gwait(flags, go, (u32)(t + 1), bid, tid, lane);

    // ---- h-quarter (ALL waves): cached block-major loads, fresh after inv.
    // h cols [hk, hk+8) live in producer chunks p0=hk/4 and p0+1:
    // chunk p = 512B at hbuf_bm + p*256 (bf16), row r at +r*4.
    {
      const u16* hb = hbuf + ((t + 1) & 1) * (BATCH * HDIM) + kq * (256 * 64) +
                      q * (2 * 256);
#pragma unroll
      for (int ks = 0; ks < 8; ++ks) {
        const u16* c0p_ = hb + ks * (8 * 256);
        u64x2 r0, r1;
        r0[0] = *(const u64*)(c0p_ + arow * 4);
        r0[1] = *(const u64*)(c0p_ + 256 + arow * 4);
        r1[0] = *(const u64*)(c0p_ + (arow + 16) * 4);
        r1[1] = *(const u64*)(c0p_ + 256 + (arow + 16) * 4);
        bf16x8 a0 = __builtin_bit_cast(bf16x8, r0);
        bf16x8 a1 = __builtin_bit_cast(bf16x8, r1);
        bf16x8 bw = *(const bf16x8*)(wph + ks * 32);
        acc0 = __builtin_amdgcn_mfma_f32_16x16x32_bf16(a0, bw, acc0, 0, 0, 0);
        acc1 = __builtin_amdgcn_mfma_f32_16x16x32_bf16(a1, bw, acc1, 0, 0, 0);
      }
    }
    // C/D layout: col = lane&15, row-in-tile = quad*4 + reg  (m89-verified)
    // cand slot = wave (8 slots x 32 local rows x 17)
    {
      float* c0p = &cand[(wave * 32 + q * 4) * 17 + ln];
      float* c1p = c0p + 16 * 17;
#pragma unroll
      for (int r = 0; r < 4; ++r) {
        c0p[r * 17] = acc0[r];
        c1p[r * 17] = acc1[r];
      }
    }
    __syncthreads();
    if (tid < 256) {
      // partials for batch pb live in waves {kq*2 + (pb>>5)}, local row pb&31
      const int mhp = pb >> 5, lr = pb & 31;
      float vi = b_i, vf = b_f, vo = b_o, vg = b_g;
#pragma unroll
      for (int p = 0; p < 4; ++p) {
        const float* cp = &cand[((p * 2 + mhp) * 32 + lr) * 17];
        vi += cp[pj];
        vf += cp[4 + pj];
        vo += cp[8 + pj];
        vg += cp[12 + pj];
      }
      float ig = sigf(vi), fg = sigf(vf), og = sigf(vo), gg = tanhf_(vg);
      float cn = ig * gg + fg * c_reg;
      float hn = og * tanhf_(cn);
      if (t < Lb) { c_reg = cn; h_reg = hn; }  // freeze past sequence end
      hstage[tid] = f2bf(h_reg);
    }
    __syncthreads();
    if (t < T_STEPS - 1) {
      if (tid < 64) {
        // publish h BLOCK-MAJOR: one coalesced 512B wave-store to 8
        // EXCLUSIVE lines (sc1 write-through to IF$; no line sharing).
        u64 v = ((const u64*)hstage)[tid];
        u64* dst =
            (u64*)(hbuf + (t & 1) * (BATCH * HDIM) + bid * 256 + tid * 4);
        __hip_atomic_store(dst, v, __ATOMIC_RELAXED, __HIP_MEMORY_SCOPE_AGENT);
      }
      __syncthreads();  // vmcnt(0) drain: publish at IF$ before arrive
      if (tid == 0)
        __hip_atomic_store(&flags[bid * FLAG_LINE_U32], (u32)(t + 2),
                           __ATOMIC_RELAXED, __HIP_MEMORY_SCOPE_AGENT);
    }
    // ---- out stores LAST (sc1, off the critical chain) ----
    if (tid < 256)
      __hip_atomic_store(&out[((size_t)t * BATCH + pb) * HDIM + bid * NJ + pj],
                         h_reg, __ATOMIC_RELAXED, __HIP_MEMORY_SCOPE_AGENT);
  }
}

extern "C" void kernel_launch(void* const* d_in, const int* in_sizes, int n_in,
                              void* d_out, int out_size, void* d_ws, size_t ws_size,
                              hipStream_t stream) {
  (void)in_sizes; (void)n_in; (void)out_size; (void)ws_size;
  const float* x = (const float*)d_in[0];
  const float* h0 = (const float*)d_in[1];
  const float* c0 = (const float*)d_in[2];
  const float* W = (const float*)d_in[3];
  const float* bias = (const float*)d_in[4];
  const int* L = (const int*)d_in[5];
  float* out = (float*)d_out;

  char* ws = (char*)d_ws;
  u32* flags = (u32*)ws;
  u16* xbf = (u16*)(ws + X_OFF);
  u16* hbuf = (u16*)(ws + H_OFF);

  hipFuncSetAttribute(reinterpret_cast<const void*>(lstm_persistent),
                      hipFuncAttributeMaxDynamicSharedMemorySize, 160 * 1024);
  hipMemsetAsync(ws, 0, 32768, stream);  // zero arrive flags + go lines
  hipLaunchKernelGGL(lstm_persistent, dim3(NBLK), dim3(THREADS), LDS_BYTES,
                     stream, x, h0, c0, W, bias, L, out, xbf, hbuf, flags);
}

// Round 9
// 2224.044 us; speedup vs baseline: 1.5481x; 1.1142x over previous
//
#include <hip/hip_runtime.h>
#include <stdint.h>

typedef unsigned short u16;
typedef unsigned int u32;
typedef unsigned long long u64;
typedef __attribute__((ext_vector_type(8))) short bf16x8;
typedef __attribute__((ext_vector_type(4))) float f32x4;
typedef __attribute__((ext_vector_type(4))) u16 u16x4;
typedef __attribute__((ext_vector_type(2))) u64 u64x2;

#define T_STEPS 256
#define BATCH 64
#define IDIM 1024
#define HDIM 1024
#define NBLK 256
#define NJ 4            // h-columns per block
#define THREADS 512
#define FLAG_LINE_U32 16                       // 64 B spacing
#define GO_U32 (NBLK * FLAG_LINE_U32)          // go lines after arrive flags
#define X_OFF 262144                           // bytes into ws (same as r1/4/5)
#define H_OFF (X_OFF + T_STEPS * BATCH * IDIM * 2)  // bytes into ws
// LDS: W fragment-major 65536 + cand 17408 + cnt 64
#define CAND_OFF 65536
#define CNT_OFF (CAND_OFF + 17408)
#define LDS_BYTES (CNT_OFF + 64)

static __device__ __forceinline__ u16 f2bf(float f) {
  u32 u = __builtin_bit_cast(u32, f);
  u += 0x7FFFu + ((u >> 16) & 1u);
  return (u16)(u >> 16);
}
static __device__ __forceinline__ float sigf(float x) {
  return __builtin_amdgcn_rcpf(1.f + __expf(-x));
}
static __device__ __forceinline__ float tanhf_(float x) {
  float ax = __builtin_fabsf(x);
  float e = __expf(-2.f * ax);
  float t = 1.f - 2.f * e * __builtin_amdgcn_rcpf(1.f + e);
  return __builtin_copysignf(t, x);
}

// ---- round-5/8 split-phase barrier (proven, unchanged mechanism) ----
// R8 post-mortem: block-major publish confirmed (WRITE -98MB). This round
// attacks the two remaining critical-path costs:
//  (1) W-LDS 8-way bank conflict: old col-major W put lane (q,ln) at bank
//      (4ln+4q)%32 -> 8 of 64 lanes per bank on EVERY ds_read_b128 of W
//      (SQ_LDS_BANK_CONFLICT 5.06e7, invariant r0-r8). New fragment-major
//      layout W[ks][lane][8]: each wave reads 1024 consecutive bytes ->
//      zero conflicts. Tile-internal index q*16+ln == lane, so the loader
//      permutation is exact.
//  (2) publish head: pointwise waves (0-3) each own 16 complete rows ->
//      shfl-pack u64 in-register, store DIRECTLY (2 exclusive lines/wave),
//      wave-local vmcnt(0), LDS-counter arrive; 4th wave fires the flag.
//      Removes hstage (2 LDS hops) + one __syncthreads from the chain head;
//      waves 4-7 proceed straight to the next x-phase.
static __device__ __forceinline__ void gwait(u32* flags, u32* go, u32 e,
                                             int bid, int tid, int lane) {
  if (bid == 0) {
    if ((tid >> 6) == 7) {  // wave 7: wave-parallel watcher
      const u32* p0 = &flags[lane * FLAG_LINE_U32];
      const u32* p1 = &flags[(lane + 64) * FLAG_LINE_U32];
      const u32* p2 = &flags[(lane + 128) * FLAG_LINE_U32];
      const u32* p3 = &flags[(lane + 192) * FLAG_LINE_U32];
      while (true) {
        u32 a = __hip_atomic_load(p0, __ATOMIC_RELAXED, __HIP_MEMORY_SCOPE_AGENT);
        u32 b = __hip_atomic_load(p1, __ATOMIC_RELAXED, __HIP_MEMORY_SCOPE_AGENT);
        u32 c = __hip_atomic_load(p2, __ATOMIC_RELAXED, __HIP_MEMORY_SCOPE_AGENT);
        u32 d = __hip_atomic_load(p3, __ATOMIC_RELAXED, __HIP_MEMORY_SCOPE_AGENT);
        int mine = (a >= e) && (b >= e) && (c >= e) && (d >= e);
        if (__all(mine)) break;
        __builtin_amdgcn_s_sleep(1);
      }
      if (lane < 8)
        __hip_atomic_store(&go[lane * FLAG_LINE_U32], e, __ATOMIC_RELAXED,
                           __HIP_MEMORY_SCOPE_AGENT);
    }
  } else {
    if (tid == 448) {  // lane 0 of wave 7: polls AFTER its x-phase (overlap)
      while (__hip_atomic_load(&go[(bid & 7) * FLAG_LINE_U32], __ATOMIC_RELAXED,
                               __HIP_MEMORY_SCOPE_AGENT) < e)
        __builtin_amdgcn_s_sleep(2);
    }
  }
  if (tid == 448)
    __builtin_amdgcn_fence(__ATOMIC_ACQUIRE, "agent");  // buffer_inv sc1
  __syncthreads();
}

// Heavy full barrier for epoch 1 only (xbf/h0 written with cached stores).
static __device__ __forceinline__ void gbar_heavy(u32* flags, u32* go, int bid,
                                                  int tid) {
  __syncthreads();
  if (tid == 0) {
    __threadfence();  // release: wbl2 so cached xbf writes visible
    __hip_atomic_store(&flags[bid * FLAG_LINE_U32], 1u, __ATOMIC_RELAXED,
                       __HIP_MEMORY_SCOPE_AGENT);
  }
  if (bid == 0) {
    if (tid < NBLK) {
      while (__hip_atomic_load(&flags[tid * FLAG_LINE_U32], __ATOMIC_RELAXED,
                               __HIP_MEMORY_SCOPE_AGENT) < 1u)
        __builtin_amdgcn_s_sleep(1);
    }
    __syncthreads();
    if (tid < 8)
      __hip_atomic_store(&go[tid * FLAG_LINE_U32], 1u, __ATOMIC_RELAXED,
                         __HIP_MEMORY_SCOPE_AGENT);
  } else {
    if (tid == 0) {
      while (__hip_atomic_load(&go[(bid & 7) * FLAG_LINE_U32], __ATOMIC_RELAXED,
                               __HIP_MEMORY_SCOPE_AGENT) < 1u)
        __builtin_amdgcn_s_sleep(2);
    }
  }
  if (tid == 0) __threadfence();  // acquire: invalidate L1/L2 before reads
  __syncthreads();
}

__global__ __launch_bounds__(THREADS, 2)
void lstm_persistent(const float* __restrict__ x, const float* __restrict__ h0,
                     const float* __restrict__ c0, const float* __restrict__ W,
                     const float* __restrict__ bias, const int* __restrict__ L,
                     float* __restrict__ out, u16* __restrict__ xbf,
                     u16* __restrict__ hbuf, u32* __restrict__ flags) {
  extern __shared__ char smem[];
  u16* Wlds = (u16*)smem;                    // [64 ks][64 lane][8] = 65536 B
  float* cand = (float*)(smem + CAND_OFF);   // [8 slot][32 row][17] = 17408 B
  u32* cnt = (u32*)(smem + CNT_OFF);         // publish-arrive counter

  u32* go = flags + GO_U32;

  const int bid = blockIdx.x;
  const int tid = threadIdx.x;
  const int wave = tid >> 6;
  const int lane = tid & 63;
  const int q = lane >> 4;   // quad 0..3
  const int ln = lane & 15;
  const int mh = wave & 1;   // M half: rows [32*mh, 32*mh+32)
  const int kq = wave >> 1;  // K quarter: x-k in [kq*256,+256), h-k same +1024
  const int arow = 32 * mh + ln;

  if (tid == 0) *cnt = 0;

  // ---- phase 0a: x -> bf16 (grid-wide), h0 -> bf16 BLOCK-MAJOR hbuf[1] ----
  {
    const int gtid = bid * THREADS + tid;
    const f32x4* xv = (const f32x4*)x;
    u16x4* ov = (u16x4*)xbf;
#pragma unroll
    for (int it = 0; it < 32; ++it) {
      int i = gtid + it * (NBLK * THREADS);
      f32x4 v = xv[i];
      u16x4 o;
      o[0] = f2bf(v[0]); o[1] = f2bf(v[1]); o[2] = f2bf(v[2]); o[3] = f2bf(v[3]);
      ov[i] = o;
    }
    if (gtid < BATCH * HDIM) {
      // block-major: h[b][j] -> hbuf[buf1][(j>>2)*256 + b*4 + (j&3)]
      int b = gtid >> 10, j = gtid & 1023;
      hbuf[BATCH * HDIM + (j >> 2) * 256 + b * 4 + (j & 3)] = f2bf(h0[gtid]);
    }
  }

  // ---- phase 0b: W slice -> LDS, FRAGMENT-MAJOR [ks][lane][8] ----
  // k = ks*32 + qq*8 + j; tile-lane = qq*16 + col. Read side: wave-uniform
  // base + lane*16B -> conflict-free ds_read_b128.
  {
    const int g = tid & 3;
    const int kq2 = tid >> 2;  // 0..127
    const f32x4* Wv = (const f32x4*)W;  // one W row = 1024 f32x4
#pragma unroll 4
    for (int i = 0; i < 16; ++i) {
      int k = kq2 + 128 * i;
      f32x4 w4 = Wv[(size_t)k * 1024 + g * 256 + bid];
      int kb = (k >> 5) * 64 + ((k >> 3) & 3) * 16;  // tile base lane index
      int ko = k & 7;
#pragma unroll
      for (int jj = 0; jj < 4; ++jj)
        Wlds[(kb + g * 4 + jj) * 8 + ko] = f2bf(w4[jj]);
    }
  }

  // ---- per-thread pointwise state (threads 0..255: (b, j) pairs) ----
  float c_reg = 0.f, h_reg = 0.f, b_i = 0.f, b_f = 0.f, b_o = 0.f, b_g = 0.f;
  int Lb = 0, pb = 0, pj = 0;
  if (tid < 256) {
    pb = tid >> 2;
    pj = tid & 3;
    int gj = bid * NJ + pj;
    Lb = L[pb];
    c_reg = c0[pb * HDIM + gj];
    h_reg = h0[pb * HDIM + gj];
    b_i = bias[0 * HDIM + gj];
    b_f = bias[1 * HDIM + gj];
    b_o = bias[2 * HDIM + gj];
    b_g = bias[3 * HDIM + gj];
  }

  gbar_heavy(flags, go, bid, tid);  // epoch 1: x/h0 visible; flags[*]=1

  const u16* wpx = Wlds + ((size_t)(kq * 8) * 64 + lane) * 8;         // x ks
  const u16* wph = Wlds + ((size_t)(32 + kq * 8) * 64 + lane) * 8;    // h ks

  for (int t = 0; t < T_STEPS; ++t) {
    f32x4 acc0 = {0.f, 0.f, 0.f, 0.f};
    f32x4 acc1 = {0.f, 0.f, 0.f, 0.f};
    // ---- x-quarter (ALL waves, h-independent): BEFORE the wait ----
    {
      const u16* pa0 =
          xbf + (size_t)t * (BATCH * IDIM) + arow * 1024 + kq * 256 + q * 8;
      const u16* pa1 = pa0 + 16 * 1024;
#pragma unroll
      for (int ks = 0; ks < 8; ++ks) {
        bf16x8 a0 = *(const bf16x8*)(pa0 + ks * 32);
        bf16x8 a1 = *(const bf16x8*)(pa1 + ks * 32);
        bf16x8 bw = *(const bf16x8*)(wpx + ks * 512);
        acc0 = __builtin_amdgcn_mfma_f32_16x16x32_bf16(a0, bw, acc0, 0, 0, 0);
        acc1 = __builtin_amdgcn_mfma_f32_16x16x32_bf16(a1, bw, acc1, 0, 0, 0);
      }
    }
    asm volatile("" ::"v"(acc0), "v"(acc1));  // pin: don't sink past wait
    __builtin_amdgcn_sched_barrier(0);

    // ---- wait for h(t-1) published (epoch t+1); t=0 covered by heavy ----
    if (t > 0) gwait(flags, go, (u32)(t + 1), bid, tid, lane);

    // ---- h-quarter (ALL waves): cached block-major loads, fresh after inv.
    {
      const u16* hb = hbuf + ((t + 1) & 1) * (BATCH * HDIM) + kq * (256 * 64) +
                      q * (2 * 256);
#pragma unroll
      for (int ks = 0; ks < 8; ++ks) {
        const u16* c0p_ = hb + ks * (8 * 256);
        u64x2 r0, r1;
        r0[0] = *(const u64*)(c0p_ + arow * 4);
        r0[1] = *(const u64*)(c0p_ + 256 + arow * 4);
        r1[0] = *(const u64*)(c0p_ + (arow + 16) * 4);
        r1[1] = *(const u64*)(c0p_ + 256 + (arow + 16) * 4);
        bf16x8 a0 = __builtin_bit_cast(bf16x8, r0);
        bf16x8 a1 = __builtin_bit_cast(bf16x8, r1);
        bf16x8 bw = *(const bf16x8*)(wph + ks * 512);
        acc0 = __builtin_amdgcn_mfma_f32_16x16x32_bf16(a0, bw, acc0, 0, 0, 0);
        acc1 = __builtin_amdgcn_mfma_f32_16x16x32_bf16(a1, bw, acc1, 0, 0, 0);
      }
    }
    // C/D layout: col = lane&15, row-in-tile = quad*4 + reg  (m89-verified)
    {
      float* c0p = &cand[(wave * 32 + q * 4) * 17 + ln];
      float* c1p = c0p + 16 * 17;
#pragma unroll
      for (int r = 0; r < 4; ++r) {
        c0p[r * 17] = acc0[r];
        c1p[r * 17] = acc1[r];
      }
    }
    __syncthreads();  // cand ready for pointwise
    if (tid < 256) {
      // partials for batch pb live in waves {p*2 + (pb>>5)}, local row pb&31
      const int mhp = pb >> 5, lr = pb & 31;
      float vi = b_i, vf = b_f, vo = b_o, vg = b_g;
#pragma unroll
      for (int p = 0; p < 4; ++p) {
        const float* cp = &cand[((p * 2 + mhp) * 32 + lr) * 17];
        vi += cp[pj];
        vf += cp[4 + pj];
        vo += cp[8 + pj];
        vg += cp[12 + pj];
      }
      float ig = sigf(vi), fg = sigf(vf), og = sigf(vo), gg = tanhf_(vg);
      float cn = ig * gg + fg * c_reg;
      float hn = og * tanhf_(cn);
      if (t < Lb) { c_reg = cn; h_reg = hn; }  // freeze past sequence end
      if (t < T_STEPS - 1) {
        // ---- register publish: pack 4 cols -> u64 (2 shfl_xor), lanes
        // pj==0 store 16 u64/wave = 2 exclusive 64B lines, sc1.
        u32 v32 = (u32)f2bf(h_reg);
        u32 a32 = v32 | (((u32)__shfl_xor((int)v32, 1)) << 16);
        u32 b32 = (u32)__shfl_xor((int)a32, 2);
        if ((tid & 3) == 0) {
          u64 hw = (u64)a32 | ((u64)b32 << 32);
          u64* hdst =
              (u64*)(hbuf + (t & 1) * (BATCH * HDIM) + bid * 256) + pb;
          __hip_atomic_store(hdst, hw, __ATOMIC_RELAXED,
                             __HIP_MEMORY_SCOPE_AGENT);
        }
        // wave-local drain: this wave's publish at IF$ before arrive
        asm volatile("s_waitcnt vmcnt(0)" ::: "memory");
        if (lane == 0) {
          u32 old = atomicAdd(cnt, 1u);
          if ((old & 3) == 3)  // 4th pointwise wave this step -> flag
            __hip_atomic_store(&flags[bid * FLAG_LINE_U32], (u32)(t + 2),
                               __ATOMIC_RELAXED, __HIP_MEMORY_SCOPE_AGENT);
        }
      }
      // ---- out stores LAST (sc1, off the critical chain) ----
      __hip_atomic_store(&out[((size_t)t * BATCH + pb) * HDIM + bid * NJ + pj],
                         h_reg, __ATOMIC_RELAXED, __HIP_MEMORY_SCOPE_AGENT);
    }
  }
}

extern "C" void kernel_launch(void* const* d_in, const int* in_sizes, int n_in,
                              void* d_out, int out_size, void* d_ws, size_t ws_size,
                              hipStream_t stream) {
  (void)in_sizes; (void)n_in; (void)out_size; (void)ws_size;
  const float* x = (const float*)d_in[0];
  const float* h0 = (const float*)d_in[1];
  const float* c0 = (const float*)d_in[2];
  const float* W = (const float*)d_in[3];
  const float* bias = (const float*)d_in[4];
  const int* L = (const int*)d_in[5];
  float* out = (float*)d_out;

  char* ws = (char*)d_ws;
  u32* flags = (u32*)ws;
  u16* xbf = (u16*)(ws + X_OFF);
  u16* hbuf = (u16*)(ws + H_OFF);

  hipFuncSetAttribute(reinterpret_cast<const void*>(lstm_persistent),
                      hipFuncAttributeMaxDynamicSharedMemorySize, 160 * 1024);
  hipMemsetAsync(ws, 0, 32768, stream);  // zero arrive flags + go lines
  hipLaunchKernelGGL(lstm_persistent, dim3(NBLK), dim3(THREADS), LDS_BYTES,
                     stream, x, h0, c0, W, bias, L, out, xbf, hbuf, flags);
}